// Round 7
// baseline (488.175 us; speedup 1.0000x reference)
//
#include <hip/hip_runtime.h>

#define N_ 65536

typedef unsigned int  uint32;
typedef unsigned short ushort;
typedef float  f32x4 __attribute__((ext_vector_type(4)));
typedef short  s16x8 __attribute__((ext_vector_type(8)));
typedef uint32 u32x2 __attribute__((ext_vector_type(2)));
typedef uint32 u32x4 __attribute__((ext_vector_type(4)));

__device__ __forceinline__ uint32 f2bf(float f){
  union{float f; uint32 i;} v; v.f=f;
  return (v.i + 0x7fffu + ((v.i>>16)&1u)) >> 16;   // RNE
}
__device__ __forceinline__ float bfl(uint32 h){     // bf16 (low 16 bits) -> float
  union{uint32 i; float f;} v; v.i = h<<16; return v.f;
}
__device__ __forceinline__ uint32 pk2(float a, float b){
  return f2bf(a) | (f2bf(b)<<16);
}
__device__ __forceinline__ f32x4 mfma16(s16x8 a, s16x8 b, f32x4 c){
  return __builtin_amdgcn_mfma_f32_16x16x32_bf16(a,b,c,0,0,0);
}
__device__ __forceinline__ s16x8 mk8(uint32 a, uint32 b, uint32 c, uint32 d){
  union{u32x4 u; s16x8 s;} v; v.u = (u32x4){a,b,c,d}; return v.s;
}

// ---------------- prep: WlT[512][256], WfxT[256][256] (bf16, k-inner), blT[512] ----------------
__global__ __launch_bounds__(256) void prep_kernel(
    const float* __restrict__ Wfx, const float* __restrict__ Wx,
    const float* __restrict__ Wsl, const float* __restrict__ bsl,
    const float* __restrict__ bx,  const float* __restrict__ temp,
    ushort* __restrict__ WlT, ushort* __restrict__ WfxT, float* __restrict__ blT)
{
  const int blk = blockIdx.x, t = threadIdx.x;
  if (blk < 512){
    const int m = blk, h = m>>6, mp = m&63;
    const float tmp = fminf(fmaxf(temp[h],0.1f),5.0f);
    float s = 0.f;
    #pragma unroll
    for (int cc=0; cc<32; cc++) s += Wx[t*256 + h*32+cc]*Wsl[cc*64+mp];
    WlT[m*256+t] = (ushort)f2bf(s/tmp);
    if (t==0){
      float bs = bsl[mp];
      for (int cc=0; cc<32; cc++) bs += bx[h*32+cc]*Wsl[cc*64+mp];
      blT[m] = bs/tmp;
    }
  } else {
    const int c = blk-512;
    WfxT[c*256+t] = (ushort)f2bf(Wfx[t*256+c]);
  }
}

// ---------------- k1a: one head per block; fused proj + softmax + slice-token partials ----------
// Block = (bh = bid&15, chunk = bid>>4); 8 tiles x 128 pts; wave w owns pts [w*16, w*16+16).
// WlT slice in REGISTERS (aWall[4][8], loaded once); WfxT_h in LDS (16 KB, staged once).
// LDS map (102400 B): [0,64K) X tile [128 rows][512B] swizzled (epilogue: per-wave pc dump at w*8K)
//                     [64K, 64K+16K) WfxT_h [32 rows][512B] swizzled (epilogue: norm scratch [8][64]f32)
//                     [80K+2K? ->] swb at 81920 + w*2560: [64 m][40B] (wave-private)
// swg2 packet layout: ushort idx = (((pb*8+h)*4+mb)*4+rg)*64 + c16*4 + j   (pb = flat_pt/16)
__global__ __launch_bounds__(512, 2)
void k1a_kernel(
    const float* __restrict__ x,
    const ushort* __restrict__ WlT,
    const ushort* __restrict__ WfxT,
    const float* __restrict__ blT,
    const float* __restrict__ bfx,
    ushort* __restrict__ swg2,      // [8192 pb][8 h][4 mb][4 rg][16 c16][4 j] bf16
    float* __restrict__ stp,        // [16 bh][64 chunk][32 c][64 m] f32
    float* __restrict__ normp)      // [16 bh][64 chunk][64 m]
{
  __shared__ __align__(16) char smem[102400];
  const int t = threadIdx.x;
  const int w = t>>6, l = t&63, rg = l>>4, c16 = l&15;
  const int bid = blockIdx.x;
  const int bh = bid & 15, chunk = bid >> 4;
  const int b = bh>>3, h = bh&7;

  char* swbb = smem + 81920 + w*2560;      // per-wave [64 m][40 B]

  // ---- stage WfxT_h -> LDS (once) ----
  #pragma unroll
  for (int p=0;p<2;p++){
    const int f = t + (p<<9);        // 0..1023
    const int row = f>>5, q = f&31;
    *(s16x8*)(smem + 65536 + (row<<9) + ((q<<4) ^ ((row&7)<<4))) =
      *(const s16x8*)(WfxT + (((h<<5)+row)<<8) + (q<<3));
  }

  // ---- WlT slice -> registers (once) ----
  s16x8 aWall[4][8];
  #pragma unroll
  for (int mf=0; mf<4; mf++)
    #pragma unroll
    for (int kb=0; kb<8; kb++)
      aWall[mf][kb] = *(const s16x8*)(WlT + (((h<<6)+(mf<<4)+c16)<<8) + (kb<<5)+(rg<<3));

  f32x4 pc[2][4];      // Phase C accumulators: rows=c (cf*16+rg*4+r), cols=m (mf*16+c16)
  #pragma unroll
  for (int i=0;i<2;i++)
    #pragma unroll
    for (int j=0;j<4;j++) pc[i][j] = (f32x4){0.f,0.f,0.f,0.f};
  f32x4 nacc[4];
  #pragma unroll
  for (int i=0;i<4;i++) nacc[i] = (f32x4){0.f,0.f,0.f,0.f};

  f32x4 blv[4];
  #pragma unroll
  for (int mf=0;mf<4;mf++) blv[mf] = *(const f32x4*)(blT + (h<<6)+(mf<<4)+(rg<<2));
  float bfv[2];
  #pragma unroll
  for (int cf=0;cf<2;cf++) bfv[cf] = bfx[(h<<5)+(cf<<4)+c16];

  const int xrow = (w<<4) + c16;
  const int xswz = (c16&7)<<4;

  for (int it=0; it<8; ++it) {
    const long gn0 = (long)b*65536 + (long)chunk*1024 + (long)it*128;   // flat b*N+n

    __syncthreads();   // S1: all waves done reading prev X tile
    // ---- stage X tile [128][256] -> bf16 LDS, XOR-swizzled ----
    {
      const float4* xs = (const float4*)(x + (gn0<<8));
      #pragma unroll
      for (int p=0;p<16;p++){
        const int f = t + (p<<9);
        const int row = f>>6, q = f&63;
        const float4 v = xs[f];
        u32x2 uu; uu.x = pk2(v.x, v.y); uu.y = pk2(v.z, v.w);
        *(u32x2*)(smem + (row<<9) + ((q<<3) ^ ((row&7)<<4))) = uu;
      }
    }
    __syncthreads();   // S2: X (and, first iter, weights) ready

    // ---- Phase A+B fused: logits^T (m x pt) and fx (pt x c) for the wave's 16 pts ----
    f32x4 accA[4], accB[2];
    #pragma unroll
    for (int mf=0;mf<4;mf++) accA[mf] = (f32x4){0.f,0.f,0.f,0.f};
    #pragma unroll
    for (int cf=0;cf<2;cf++) accB[cf] = (f32x4){0.f,0.f,0.f,0.f};
    #pragma unroll
    for (int kb=0;kb<8;kb++){
      const s16x8 xv = *(const s16x8*)(smem + (xrow<<9) + (((kb<<6)+(rg<<4)) ^ xswz));
      s16x8 bW0, bW1;
      {
        const int r0 = c16, r1 = 16+c16;
        bW0 = *(const s16x8*)(smem + 65536 + (r0<<9) + (((kb<<6)+(rg<<4)) ^ ((r0&7)<<4)));
        bW1 = *(const s16x8*)(smem + 65536 + (r1<<9) + (((kb<<6)+(rg<<4)) ^ ((r1&7)<<4)));
      }
      #pragma unroll
      for (int mf=0;mf<4;mf++)
        accA[mf] = mfma16(aWall[mf][kb], xv, accA[mf]);
      accB[0] = mfma16(xv, bW0, accB[0]);
      accB[1] = mfma16(xv, bW1, accB[1]);
    }

    // ---- softmax over m (4 m-frags in-reg x 4 rg-groups cross-lane), pt = c16 ----
    {
      f32x4 v[4];
      float mx = -3.0e38f;
      #pragma unroll
      for (int mf=0;mf<4;mf++){
        v[mf] = accA[mf] + blv[mf];
        mx = fmaxf(mx, fmaxf(fmaxf(v[mf].x, v[mf].y), fmaxf(v[mf].z, v[mf].w)));
      }
      mx = fmaxf(mx, __shfl_xor(mx,16));
      mx = fmaxf(mx, __shfl_xor(mx,32));
      float s = 0.f;
      #pragma unroll
      for (int mf=0;mf<4;mf++){
        v[mf].x = __expf(v[mf].x-mx); v[mf].y = __expf(v[mf].y-mx);
        v[mf].z = __expf(v[mf].z-mx); v[mf].w = __expf(v[mf].w-mx);
        s += v[mf].x+v[mf].y+v[mf].z+v[mf].w;
      }
      s += __shfl_xor(s,16);
      s += __shfl_xor(s,32);
      const float inv = 1.0f/s;
      const long pbh8 = (((gn0>>4) + w)<<3) + h;
      #pragma unroll
      for (int mf=0;mf<4;mf++){
        f32x4 sv = v[mf]*inv;
        nacc[mf] += sv;
        u32x2 p; p.x = pk2(sv.x, sv.y); p.y = pk2(sv.z, sv.w);
        // coalesced packet store: 64 lanes cover 512 contiguous bytes
        *(u32x2*)(swg2 + (((pbh8<<2)+mf)<<8) + (rg<<6) + (c16<<2)) = p;
        // pair-pack transpose (regs=m) -> swb [m][pt]
        const uint32 px = (uint32)__shfl_xor((int)p.x, 1);
        const uint32 py = (uint32)__shfl_xor((int)p.y, 1);
        const bool ev = ((c16&1)==0);
        const uint32 s0 = ev ? (uint32)p.x : py;
        const uint32 s1 = ev ? px : (uint32)p.y;
        const uint32 wA = (s0 & 0xffffu) | (s1<<16);
        const uint32 wB = (s0>>16) | (s1 & 0xffff0000u);
        const int rowA = (mf<<4) + (rg<<2) + (ev?0:2);
        const int cbyt = (c16 & ~1) << 1;
        *(uint32*)(swbb + rowA*40 + 40 + cbyt - 40) = wA;      // rowA*40 + cbyt
        *(uint32*)(swbb + (rowA+1)*40 + cbyt) = wB;
      }
    }

    // ---- Phase C: A = {fx_hi, fx_lo} in-reg (identity of D/A layouts); B = sw dup ----
    u32x4 afu[2];
    #pragma unroll
    for (int cf=0;cf<2;cf++){
      const float v0 = accB[cf].x+bfv[cf], v1 = accB[cf].y+bfv[cf];
      const float v2 = accB[cf].z+bfv[cf], v3 = accB[cf].w+bfv[cf];
      const uint32 h0=f2bf(v0), h1=f2bf(v1), h2=f2bf(v2), h3=f2bf(v3);
      afu[cf].x = h0|(h1<<16);
      afu[cf].y = h2|(h3<<16);
      afu[cf].z = f2bf(v0-bfl(h0)) | (f2bf(v1-bfl(h1))<<16);
      afu[cf].w = f2bf(v2-bfl(h2)) | (f2bf(v3-bfl(h3))<<16);
    }
    asm volatile("s_waitcnt lgkmcnt(0)" ::: "memory");   // swb writes done before reads
    __builtin_amdgcn_sched_barrier(0);
    #pragma unroll
    for (int mf=0; mf<4; mf++){
      const u32x2 q = *(const u32x2*)(swbb + ((mf<<4)+c16)*40 + (rg<<3));
      const s16x8 bdup = mk8(q.x, q.y, q.x, q.y);
      pc[0][mf] = mfma16(mk8(afu[0].x,afu[0].y,afu[0].z,afu[0].w), bdup, pc[0][mf]);
      pc[1][mf] = mfma16(mk8(afu[1].x,afu[1].y,afu[1].z,afu[1].w), bdup, pc[1][mf]);
    }
  } // tiles

  // ---- epilogue: per-wave pc dump (own X rows), block reduce, norm reduce ----
  #pragma unroll
  for (int cf=0;cf<2;cf++)
    #pragma unroll
    for (int mf=0;mf<4;mf++)
      #pragma unroll
      for (int r=0;r<4;r++){
        const int cc = (cf<<4)+(rg<<2)+r;
        *(float*)(smem + (w<<13) + (((cc<<6) + (mf<<4) + c16)<<2)) = pc[cf][mf][r];
      }
  __syncthreads();   // E1: pc dumps visible; weights region dead

  // norm: reduce over c16 lanes, dump per wave to weights region [8 w][64 m] f32
  #pragma unroll
  for (int mf=0;mf<4;mf++){
    #pragma unroll
    for (int d=1; d<16; d<<=1){
      nacc[mf].x += __shfl_xor(nacc[mf].x, d);
      nacc[mf].y += __shfl_xor(nacc[mf].y, d);
      nacc[mf].z += __shfl_xor(nacc[mf].z, d);
      nacc[mf].w += __shfl_xor(nacc[mf].w, d);
    }
  }
  if (c16==0){
    #pragma unroll
    for (int mf=0;mf<4;mf++)
      *(f32x4*)(smem + 65536 + (w<<8) + (((mf<<4)+(rg<<2))<<2)) = nacc[mf];
  }
  // stp: sum 8 waves' [32 c][64 m] dumps
  {
    f32x4 s = (f32x4){0.f,0.f,0.f,0.f};
    #pragma unroll
    for (int w2=0; w2<8; w2++)
      s += *(const f32x4*)(smem + (w2<<13) + (t<<4));
    *(f32x4*)(stp + ((size_t)((bh<<6)+chunk)<<11) + (t<<2)) = s;
  }
  __syncthreads();   // E2: norm dumps visible
  if (t<64){
    float s = 0.f;
    #pragma unroll
    for (int w2=0; w2<8; w2++)
      s += *(const float*)(smem + 65536 + (w2<<8) + (t<<2));
    normp[((size_t)((bh<<6)+chunk)<<6) + t] = s;
  }
}

// ---------------- k2: final reduce + tiny attention + fold W_out -> OS2T hi/lo bf16 -------------
__global__ __launch_bounds__(256) void k2_kernel(
    const float* __restrict__ stp, const float* __restrict__ normp,
    const float* __restrict__ Wq, const float* __restrict__ Wk, const float* __restrict__ Wv,
    const float* __restrict__ Wout, ushort* __restrict__ OS2Th, ushort* __restrict__ OS2Tl)
{
  __shared__ float nrmL[64];
  __shared__ float tok[2048];
  __shared__ float qL[2048], kL[2048], vL[2048];
  __shared__ float sc[4096];
  __shared__ float osL[2048];
  const int bh = blockIdx.x; const int b = bh>>3, h = bh&7;
  const int t = threadIdx.x;

  if (t<64){
    float s = 0.f;
    for (int ch=0; ch<64; ch++) s += normp[((size_t)((bh<<6)+ch)<<6) + t];
    nrmL[t] = s;
  }
  __syncthreads();
  {
    f32x4 a0 = {0,0,0,0}, a1 = {0,0,0,0};
    for (int ch=0; ch<64; ch++){
      const f32x4* p = (const f32x4*)(stp + ((size_t)((bh<<6)+ch)<<11) + (t<<3));
      a0 += p[0]; a1 += p[1];
    }
    const int c = t>>3, m0 = (t&7)<<3;
    #pragma unroll
    for (int j=0;j<4;j++) tok[(m0+j)*32 + c]   = a0[j] / (nrmL[m0+j]   + 1e-5f);
    #pragma unroll
    for (int j=0;j<4;j++) tok[(m0+4+j)*32 + c] = a1[j] / (nrmL[m0+4+j] + 1e-5f);
  }
  __syncthreads();

  const int g = t>>2, q4 = t&3;
  float aq[8]={0,0,0,0,0,0,0,0}, ak2[8]={0,0,0,0,0,0,0,0}, av[8]={0,0,0,0,0,0,0,0};
  for (int kk=0; kk<32; kk++){
    const float tv = tok[(g<<5)+kk];
    const int wo = kk*32 + (q4<<3);
    #pragma unroll
    for (int j=0;j<8;j++){
      aq[j]  = fmaf(tv, Wq[wo+j], aq[j]);
      ak2[j] = fmaf(tv, Wk[wo+j], ak2[j]);
      av[j]  = fmaf(tv, Wv[wo+j], av[j]);
    }
  }
  #pragma unroll
  for (int j=0;j<8;j++){
    qL[(g<<5)+(q4<<3)+j]=aq[j];
    kL[(g<<5)+(q4<<3)+j]=ak2[j];
    vL[(g<<5)+(q4<<3)+j]=av[j];
  }
  __syncthreads();

  const float scale = 0.17677669529663689f;
  float svv[16]; float mx = -3.0e38f;
  for (int mm=0;mm<16;mm++){
    const int m = (q4<<4)+mm;
    float s2 = 0.f;
    #pragma unroll
    for (int c=0;c<32;c++) s2 = fmaf(qL[(g<<5)+c], kL[(m<<5)+c], s2);
    s2 *= scale;
    svv[mm] = s2; mx = fmaxf(mx, s2);
  }
  mx = fmaxf(mx, __shfl_xor(mx,1));
  mx = fmaxf(mx, __shfl_xor(mx,2));
  float ssum = 0.f;
  for (int mm=0;mm<16;mm++){ svv[mm] = __expf(svv[mm]-mx); ssum += svv[mm]; }
  ssum += __shfl_xor(ssum,1); ssum += __shfl_xor(ssum,2);
  const float isum = 1.0f/ssum;
  for (int mm=0;mm<16;mm++) sc[(g<<6) + (q4<<4) + mm] = svv[mm]*isum;
  __syncthreads();

  float os[8]={0,0,0,0,0,0,0,0};
  for (int m=0;m<64;m++){
    const float a = sc[(g<<6)+m];
    const int vo = (m<<5)+(q4<<3);
    #pragma unroll
    for (int j=0;j<8;j++) os[j] = fmaf(a, vL[vo+j], os[j]);
  }
  #pragma unroll
  for (int j=0;j<8;j++) osL[(g<<5)+(q4<<3)+j] = os[j];
  __syncthreads();

  // OS2T{h,l}[b][d][h*64+g] = sum_c os[g][c] * Wout[h*32+c][d]  (split bf16)
  const int d = t;
  float wcol[32];
  #pragma unroll
  for (int c=0;c<32;c++) wcol[c] = Wout[(h*32+c)*256 + d];
  uint32* orh = (uint32*)(OS2Th + ((size_t)(b*256+d))*512 + h*64);
  uint32* orl = (uint32*)(OS2Tl + ((size_t)(b*256+d))*512 + h*64);
  #pragma unroll 4
  for (int g2=0; g2<32; g2++){
    float s0=0.f, s1=0.f;
    #pragma unroll
    for (int c=0;c<32;c++){
      s0 = fmaf(osL[((g2*2  )<<5)+c], wcol[c], s0);
      s1 = fmaf(osL[((g2*2+1)<<5)+c], wcol[c], s1);
    }
    const uint32 h0 = f2bf(s0), h1 = f2bf(s1);
    orh[g2] = h0 | (h1<<16);
    orl[g2] = f2bf(s0 - bfl(h0)) | (f2bf(s1 - bfl(h1)) << 16);
  }
}

// ---------------- k3: out = sw @ (OS2Th+OS2Tl)^T + b_out (register MFMA GEMM) -------------------
__global__ __launch_bounds__(256) void k3_kernel(
    const ushort* __restrict__ swg2,
    const ushort* __restrict__ OS2Th,
    const ushort* __restrict__ OS2Tl,
    const float* __restrict__ bout,
    float* __restrict__ out)
{
  const int t = threadIdx.x, w = t>>6, l = t&63, rg = l>>4, c16 = l&15;
  const int blk = blockIdx.x;
  const long gn0 = (long)blk<<7;
  const int b = blk>>9;
  f32x4 acc[8][4];
  #pragma unroll
  for (int r=0;r<8;r++)
    #pragma unroll
    for (int c=0;c<4;c++) acc[r][c] = (f32x4){0.f,0.f,0.f,0.f};
  const long obb = (((long)(b<<8) + (w<<6))<<9);
  for (int kb=0;kb<16;kb++){
    const int h3 = kb>>1;
    const int mb = ((kb&1)<<1) + (rg>>1);
    const int pkt = (rg&1)<<1;
    s16x8 aS[8];
    #pragma unroll
    for (int r=0;r<8;r++){
      const long pb = (gn0>>4) + r;
      const ushort* bp = swg2 + ((((pb<<3)+h3)<<2) + mb)*256 + (c16<<2);
      const u32x2 lo = *(const u32x2*)(bp + (pkt<<6));
      const u32x2 hi = *(const u32x2*)(bp + ((pkt+1)<<6));
      aS[r] = mk8(lo.x, lo.y, hi.x, hi.y);
    }
    #pragma unroll
    for (int c=0;c<4;c++){
      const long ro = obb + ((long)((c<<4)+c16)<<9) + (kb<<5)+(rg<<3);
      const s16x8 bhv = *(const s16x8*)(OS2Th + ro);
      const s16x8 blv = *(const s16x8*)(OS2Tl + ro);
      #pragma unroll
      for (int r=0;r<8;r++)
        acc[r][c] = mfma16(aS[r], bhv, acc[r][c]);
      #pragma unroll
      for (int r=0;r<8;r++)
        acc[r][c] = mfma16(aS[r], blv, acc[r][c]);
    }
  }
  float bo[4];
  #pragma unroll
  for (int c=0;c<4;c++) bo[c] = bout[(w<<6)+(c<<4)+c16];
  #pragma unroll
  for (int r=0;r<8;r++)
    #pragma unroll
    for (int c=0;c<4;c++)
      #pragma unroll
      for (int rr=0;rr<4;rr++)
        out[((gn0 + (r<<4)+(rg<<2)+rr)<<8) + (w<<6)+(c<<4)+c16] = acc[r][c][rr] + bo[c];
}

extern "C" void kernel_launch(void* const* d_in, const int* in_sizes, int n_in,
                              void* d_out, int out_size, void* d_ws, size_t ws_size,
                              hipStream_t stream)
{
  const float* x     = (const float*)d_in[0];
  const float* Wfx   = (const float*)d_in[1];
  const float* bfx   = (const float*)d_in[2];
  const float* Wx    = (const float*)d_in[3];
  const float* bx    = (const float*)d_in[4];
  const float* Wsl   = (const float*)d_in[5];
  const float* bsl   = (const float*)d_in[6];
  const float* temp  = (const float*)d_in[7];
  const float* Wq    = (const float*)d_in[8];
  const float* Wk    = (const float*)d_in[9];
  const float* Wv    = (const float*)d_in[10];
  const float* Wout  = (const float*)d_in[11];
  const float* bout  = (const float*)d_in[12];
  float* out = (float*)d_out;

  char* ws = (char*)d_ws;
  // ws layout (bytes), total 144,312,320:
  ushort* WlT   = (ushort*)(ws);                   // 262144
  ushort* WfxT  = (ushort*)(ws + 262144);          // 131072
  float*  blT   = (float*) (ws + 393216);          // 2048
  ushort* swg2  = (ushort*)(ws + 395264);          // 134217728
  float*  stp   = (float*) (ws + 134612992);       // 8388608
  float*  normp = (float*) (ws + 143001600);       // 262144
  ushort* OS2Th = (ushort*)(ws + 143263744);       // 524288
  ushort* OS2Tl = (ushort*)(ws + 143788032);       // 524288

  prep_kernel<<<dim3(768), dim3(256), 0, stream>>>(Wfx, Wx, Wsl, bsl, bx, temp, WlT, WfxT, blT);
  k1a_kernel<<<dim3(1024), dim3(512), 0, stream>>>(x, WlT, WfxT, blT, bfx, swg2, stp, normp);
  k2_kernel<<<dim3(16), dim3(256), 0, stream>>>(stp, normp, Wq, Wk, Wv, Wout, OS2Th, OS2Tl);
  k3_kernel<<<dim3(1024), dim3(256), 0, stream>>>(swg2, OS2Th, OS2Tl, bout, out);
}